// Round 9
// baseline (231.637 us; speedup 1.0000x reference)
//
#include <hip/hip_runtime.h>
#include <cstdint>
#include <cstddef>
#include <math.h>

#define NN   4096
#define DD   256
#define E0S  131072
#define NE   (E0S + NN)     // 135168 edges incl. self loops
#define KK   2048
#define NEG_SLOPE 0.2f
#define SEGCAP 256          // max segment length staged in LDS

typedef float floatx4 __attribute__((ext_vector_type(4)));   // clang-native vec4

// edge accessors: e < E0S -> from input arrays; else self-loop (e - E0S)
__device__ __forceinline__ int esrc(const int* s, int e){ return e < E0S ? s[e] : e - E0S; }
__device__ __forceinline__ int edst(const int* d, int e){ return e < E0S ? d[e] : e - E0S; }

// ---------------- init: zero degree arrays, colmap=-1, (optionally) zero A_c ------------
__global__ void init_kernel(int* deg_dst, int* deg_src, int* colmap, float* Ac, int zero_ac){
    int i = blockIdx.x * blockDim.x + threadIdx.x;
    int stride = gridDim.x * blockDim.x;
    if (zero_ac){
        for (size_t t = i; t < (size_t)KK * KK; t += stride) Ac[t] = 0.f;
    }
    for (int t = i; t < NN; t += stride){ deg_dst[t] = 0; deg_src[t] = 0; colmap[t] = -1; }
}

// ---------------- degree count ----------------
__global__ void count_kernel(const int* e_src, const int* e_dst, int* deg_dst, int* deg_src){
    int e = blockIdx.x * blockDim.x + threadIdx.x;
    if (e < NE){
        atomicAdd(&deg_dst[edst(e_dst, e)], 1);
        atomicAdd(&deg_src[esrc(e_src, e)], 1);
    }
}

// ---------------- exclusive scan of degrees (one block per array) ----------------
__global__ void __launch_bounds__(1024) scan_kernel(const int* degA, int* offA, int* curA,
                                                    const int* degB, int* offB, int* curB){
    const int* deg = (blockIdx.x == 0) ? degA : degB;
    int* off = (blockIdx.x == 0) ? offA : offB;
    int* cur = (blockIdx.x == 0) ? curA : curB;
    __shared__ int part[1024];
    int t = threadIdx.x;
    int base = t * 4;
    int s0 = deg[base], s1 = deg[base+1], s2 = deg[base+2], s3 = deg[base+3];
    int tot = s0 + s1 + s2 + s3;
    part[t] = tot;
    __syncthreads();
    for (int d = 1; d < 1024; d <<= 1){
        int v = (t >= d) ? part[t - d] : 0;
        __syncthreads();
        part[t] += v;
        __syncthreads();
    }
    int excl = part[t] - tot;
    off[base]   = excl;            cur[base]   = excl;
    off[base+1] = excl + s0;       cur[base+1] = excl + s0;
    off[base+2] = excl + s0 + s1;  cur[base+2] = excl + s0 + s1;
    off[base+3] = excl + s0 + s1 + s2; cur[base+3] = excl + s0 + s1 + s2;
    if (t == 1023) off[NN] = part[1023];
}

// ---------------- CSR fill ----------------
__global__ void fill_kernel(const int* e_src, const int* e_dst, int* cur_dst, int* cur_src,
                            int* eid_dst, int* eid_src){
    int e = blockIdx.x * blockDim.x + threadIdx.x;
    if (e < NE){
        int p = atomicAdd(&cur_dst[edst(e_dst, e)], 1); eid_dst[p] = e;
        int q = atomicAdd(&cur_src[esrc(e_src, e)], 1); eid_src[q] = e;
    }
}

// ---------------- sort each CSR segment ascending (determinism): rank-by-count ----------
// also emits isd[u] = src node at dst-CSR position u
__global__ void segsort_kernel(const int* off_dst, int* eid_dst, const int* off_src, int* eid_src,
                               const int* e_src, int* isd){
    __shared__ int buf[4][SEGCAP];
    int wid  = (blockIdx.x * blockDim.x + threadIdx.x) >> 6;   // global wave id in [0, 2*NN)
    int lane = threadIdx.x & 63;
    int w    = threadIdx.x >> 6;
    const int* off; int* eid; int n; bool isdst;
    if (wid < NN){ off = off_dst; eid = eid_dst; n = wid; isdst = true; }
    else         { off = off_src; eid = eid_src; n = wid - NN; isdst = false; }
    int lo = off[n], hi = off[n+1];
    int L = hi - lo;
    int Lc = (L <= SEGCAP) ? L : SEGCAP;
    for (int i = lane; i < Lc; i += 64) buf[w][i] = eid[lo + i];
    __syncthreads();
    if (L <= SEGCAP){
        for (int i = lane; i < L; i += 64){
            int v = buf[w][i];
            int r = 0;
            for (int j = 0; j < L; ++j) r += (buf[w][j] < v);
            eid[lo + r] = v;
            if (isdst) isd[lo + r] = esrc(e_src, v);
        }
    } else if (lane == 0){
        // pathological fallback (never expected at this size)
        for (int i = lo + 1; i < hi; ++i){
            int v = eid[i]; int j = i - 1;
            while (j >= lo && eid[j] > v){ eid[j+1] = eid[j]; --j; }
            eid[j+1] = v;
        }
        if (isdst) for (int i = lo; i < hi; ++i) isd[i] = esrc(e_src, eid[i]);
    }
}

// ---------------- fused: segment_max -> lin -> attention dots (8 nodes per block) --------
// replaces segmax_kernel + lin_kernel + nodedots_kernel; x_q / x_ql never materialized.
// All arithmetic orders identical to the previous separate kernels.
#define LROWS 8
__global__ void sml_kernel(const float* x, const int* off, const int* isd,
                           const float* lin_w, const float* lin_b, const float* att_w,
                           float* q_s, float* p_s){
    __shared__ float xs[LROWS][DD];
    __shared__ int   is_[SEGCAP];
    __shared__ float s1[256], s2[256];
    int col = threadIdx.x;
    int r0 = blockIdx.x * LROWS;
    // phase 1: segment max per node (max is exact -> order-insensitive)
    for (int r = 0; r < LROWS; ++r){
        int n = r0 + r;
        int lo = off[n], hi = off[n+1];
        int L = hi - lo;
        int Ls = (L <= SEGCAP) ? L : SEGCAP;
        for (int t = col; t < Ls; t += 256) is_[t] = isd[lo + t];
        __syncthreads();
        float m = -INFINITY;
        int t = 0;
        for (; t + 1 < Ls; t += 2){
            float v0 = x[(size_t)is_[t]   * DD + col];
            float v1 = x[(size_t)is_[t+1] * DD + col];
            m = fmaxf(m, fmaxf(v0, v1));
        }
        if (t < Ls) m = fmaxf(m, x[(size_t)is_[t] * DD + col]);
        for (t = Ls; t < L; ++t)  // overflow fallback
            m = fmaxf(m, x[(size_t)isd[lo + t] * DD + col]);
        xs[r][col] = m;
        __syncthreads();
    }
    // phase 2: lin (exact order of old lin_kernel: bc then k ascending)
    float acc[LROWS];
    float bc = lin_b[col];
    #pragma unroll
    for (int r = 0; r < LROWS; ++r) acc[r] = bc;
    for (int kk = 0; kk < DD; ++kk){
        float wv = lin_w[(size_t)kk * DD + col];
        #pragma unroll
        for (int r = 0; r < LROWS; ++r) acc[r] = fmaf(xs[r][kk], wv, acc[r]);
    }
    // phase 3: attention dots (exact tree of old nodedots_kernel)
    float aw1 = att_w[col];
    float aw2 = att_w[DD + col];
    for (int r = 0; r < LROWS; ++r){
        int n = r0 + r;
        s1[col] = acc[r] * aw1;
        s2[col] = x[(size_t)n * DD + col] * aw2;
        __syncthreads();
        for (int d = 128; d > 0; d >>= 1){
            if (col < d){ s1[col] += s1[col + d]; s2[col] += s2[col + d]; }
            __syncthreads();
        }
        if (col == 0){ q_s[n] = s1[0]; p_s[n] = s2[0]; }
        __syncthreads();
    }
}

// ---------------- fused: per-dst softmax -> xn segment-sum -> LEConv dots (1 node/block) --
// softmax arithmetic copied verbatim (wave 0 only); xn + dots identical to old xnfit.
__global__ void softxn_kernel(const float* x, const int* off, const int* eid, const int* isd,
                              const float* q_s, const float* p_s, const float* att_b,
                              const float* le1_w, const float* le1_b, const float* le2_w,
                              const float* le3_w, const float* le3_b,
                              float* sc, float* ssd, float* xn,
                              float* a_, float* b_, float* c_){
    __shared__ int   is_[SEGCAP];
    __shared__ float ss_[SEGCAP];
    __shared__ float s1[256], s2[256], s3[256];
    int n = blockIdx.x, col = threadIdx.x;
    int lo = off[n], hi = off[n+1];
    int L = hi - lo;
    int Ls = (L <= SEGCAP) ? L : SEGCAP;
    for (int t = col; t < Ls; t += 256) is_[t] = isd[lo + t];
    __syncthreads();
    if (col < 64){
        int lane = col;
        float ab = att_b[0];
        float qn = q_s[n];
        float m = -INFINITY;
        for (int t = lane; t < L; t += 64){
            int sn = (t < Ls) ? is_[t] : isd[lo + t];
            float s = qn + p_s[sn] + ab;
            s = (s > 0.f) ? s : NEG_SLOPE * s;
            m = fmaxf(m, s);
        }
        #pragma unroll
        for (int d = 32; d > 0; d >>= 1) m = fmaxf(m, __shfl_xor(m, d));
        float sum = 0.f;
        for (int t = lane; t < L; t += 64){
            int sn = (t < Ls) ? is_[t] : isd[lo + t];
            float s = qn + p_s[sn] + ab;
            s = (s > 0.f) ? s : NEG_SLOPE * s;
            float ex = expf(s - m);
            if (t < Ls) ss_[t] = ex; else ssd[lo + t] = ex;
            sum += ex;
        }
        #pragma unroll
        for (int d = 32; d > 0; d >>= 1) sum += __shfl_xor(sum, d);
        float inv = 1.f / sum;
        for (int t = lane; t < L; t += 64){
            float v = ((t < Ls) ? ss_[t] : ssd[lo + t]) * inv;
            if (t < Ls) ss_[t] = v;
            ssd[lo + t] = v;          // position-indexed (spgemm2)
            sc[eid[lo + t]] = v;      // edge-indexed (prepsrc)
        }
    }
    __syncthreads();
    // xn accumulation (identical order to old xnfit_kernel)
    float acc = 0.f;
    int t = 0;
    for (; t + 1 < Ls; t += 2){
        float v0 = x[(size_t)is_[t]   * DD + col];
        float v1 = x[(size_t)is_[t+1] * DD + col];
        acc = fmaf(ss_[t],   v0, acc);
        acc = fmaf(ss_[t+1], v1, acc);
    }
    if (t < Ls) acc = fmaf(ss_[t], x[(size_t)is_[t] * DD + col], acc);
    for (t = Ls; t < L; ++t)             // overflow fallback
        acc = fmaf(ssd[lo + t], x[(size_t)isd[lo + t] * DD + col], acc);
    xn[(size_t)n * DD + col] = acc;
    // fused LEConv dots (same tree reduction -> identical numerics)
    s1[col] = acc * le1_w[col];
    s2[col] = acc * le2_w[col];
    s3[col] = acc * le3_w[col];
    __syncthreads();
    for (int dd = 128; dd > 0; dd >>= 1){
        if (col < dd){ s1[col] += s1[col+dd]; s2[col] += s2[col+dd]; s3[col] += s3[col+dd]; }
        __syncthreads();
    }
    if (col == 0){
        a_[n] = s1[0] + le1_b[0];
        b_[n] = s2[0];
        c_[n] = s3[0] + le3_b[0];
    }
}

// ---------------- fitness = sigmoid(segsum(a[src]-b[dst]) + c) (one wave per node) --------
__global__ void fitness_kernel(const int* off, const int* isd,
                               const float* a_, const float* b_, const float* c_,
                               float* fit){
    int wave = threadIdx.x >> 6;
    int lane = threadIdx.x & 63;
    int n = blockIdx.x * 4 + wave;
    int lo = off[n], hi = off[n+1];
    float bn = b_[n];
    float s = 0.f;
    for (int t = lo + lane; t < hi; t += 64){
        s += a_[isd[t]] - bn;
    }
    #pragma unroll
    for (int d = 32; d > 0; d >>= 1) s += __shfl_xor(s, d);
    if (lane == 0){
        float z = s + c_[n];
        fit[n] = 1.f / (1.f + expf(-z));
    }
}

// ---------------- top-k via bitonic sort of (value desc, idx asc) keys ----------------
__global__ void __launch_bounds__(1024) topk_kernel(const float* fit, int* perm, int* colmap,
                                                    float* out_perm){
    __shared__ unsigned long long keys[NN];
    int t = threadIdx.x;
    for (int i = t; i < NN; i += 1024){
        unsigned int u = __float_as_uint(fit[i]);
        u = (u & 0x80000000u) ? ~u : (u | 0x80000000u);  // monotone map
        u = ~u;                                           // descending
        keys[i] = ((unsigned long long)u << 32) | (unsigned int)i;
    }
    __syncthreads();
    for (unsigned int ssize = 2; ssize <= NN; ssize <<= 1){
        for (unsigned int stride = ssize >> 1; stride > 0; stride >>= 1){
            for (int i = t; i < NN / 2; i += 1024){
                unsigned int idx = 2u * i - (i & (stride - 1u));
                unsigned int par = idx + stride;
                bool asc = ((idx & ssize) == 0u);
                unsigned long long a = keys[idx], b = keys[par];
                if ((a > b) == asc){ keys[idx] = b; keys[par] = a; }
            }
            __syncthreads();
        }
    }
    for (int i = t; i < KK; i += 1024){
        int node = (int)(keys[i] & 0xFFFFFFFFull);
        perm[i] = node;
        colmap[node] = i;
        out_perm[i] = (float)node;
    }
}

// ---------------- fused: x_out gather + src-side prep (cp/sp) ----------------
__global__ void xoutprep_kernel(const float* xn, const float* fit, const int* perm, float* x_out,
                                const int* eid_src, const int* e_dst, const int* colmap,
                                const float* sc, int* cp, float* sp){
    int b = blockIdx.x;
    if (b < KK){
        int r = b, d = threadIdx.x;
        int p = perm[r];
        x_out[(size_t)r * DD + d] = xn[(size_t)p * DD + d] * fit[p];
    } else {
        int u = (b - KK) * 256 + threadIdx.x;
        if (u < NE){
            int f = eid_src[u];
            cp[u] = colmap[edst(e_dst, f)];
            sp[u] = sc[f];
        }
    }
}

// ---------------- T[i,:] = sum over out-edges e=(i,j): w_e * Sp[j,:]  (row in LDS) -------
// 32-lane sub-waves: 8 segments in flight (deg~33 -> ~full lane utilization).
__global__ void spgemm1_kernel(const int* e_dst, const float* ew,
                               const int* off_src, const int* eid_src,
                               const int* cp, const float* sp, float* T){
    __shared__ float row[KK];
    __shared__ int   jlo_[SEGCAP];
    __shared__ int   jhi_[SEGCAP];
    __shared__ float w_[SEGCAP];
    int i = blockIdx.x;
    for (int c = threadIdx.x; c < KK; c += 256) row[c] = 0.f;
    int lo = off_src[i], hi = off_src[i+1];
    int L = hi - lo;
    int Ls = (L <= SEGCAP) ? L : SEGCAP;
    for (int t = threadIdx.x; t < Ls; t += 256){
        int e = eid_src[lo + t];
        int j = edst(e_dst, e);
        jlo_[t] = off_src[j];
        jhi_[t] = off_src[j+1];
        w_[t]   = (e < E0S) ? ew[e] : 1.0f;
    }
    __syncthreads();
    int sw = threadIdx.x >> 5, ln = threadIdx.x & 31;
    for (int t = sw; t < Ls; t += 8){
        float w1 = w_[t];
        for (int u = jlo_[t] + ln; u < jhi_[t]; u += 32){
            int c = cp[u];                       // contiguous stream
            if (c >= 0) atomicAdd(&row[c], w1 * sp[u]);
        }
    }
    for (int t = Ls + sw; t < L; t += 8){   // overflow fallback
        int e = eid_src[lo + t];
        int j = edst(e_dst, e);
        float w1 = (e < E0S) ? ew[e] : 1.0f;
        int jlo = off_src[j], jhi = off_src[j+1];
        for (int u = jlo + ln; u < jhi; u += 32){
            int c = cp[u];
            if (c >= 0) atomicAdd(&row[c], w1 * sp[u]);
        }
    }
    __syncthreads();
    float* Trow = T + (size_t)i * KK;
    for (int c = threadIdx.x; c < KK; c += 256) Trow[c] = row[c];
}

// ---------------- A_c[r, chunk] = sum over dst-positions of perm[r]: ssd * T[isd, chunk] ----
// 16 chunks of 128 cols (2 MB T-slice << 4 MB XCD L2). grid dim3(8, 512), 256 thr:
// chunk = bx + 8*(by>>8) -> linear id % 8 = bx pins each chunk's slice to one XCD.
// Each block: 8 rows (32 lanes/row), floatx4 (4 cols) per thread. Nontemporal Ac store.
__global__ void spgemm2_kernel(const int* perm, const int* off_dst,
                               const int* isd, const float* ssd,
                               const float* T, float* Ac){
    __shared__ int   is_[8][SEGCAP];
    __shared__ float ss_[8][SEGCAP];
    int bx = blockIdx.x;              // 0..7
    int by = blockIdx.y;              // 0..511
    int half = by >> 8;               // 0 or 1
    int rr   = by & 255;              // 0..255
    int sub  = threadIdx.x >> 5;      // 0..7 (row within block)
    int lane = threadIdx.x & 31;      // 0..31
    int r = rr * 8 + sub;
    int chunk = bx + 8 * half;        // 0..15
    int c0 = chunk * 128 + lane * 4;  // 4 consecutive columns per thread
    int node = perm[r];
    int lo = off_dst[node], hi = off_dst[node+1];
    int L = hi - lo;
    int Ls = (L <= SEGCAP) ? L : SEGCAP;
    for (int t = lane; t < Ls; t += 32){
        is_[sub][t] = isd[lo + t];
        ss_[sub][t] = ssd[lo + t];
    }
    __syncthreads();
    floatx4 acc = {0.f, 0.f, 0.f, 0.f};
    int t = 0;
    for (; t + 1 < Ls; t += 2){
        floatx4 a = *(const floatx4*)&T[(size_t)is_[sub][t]   * KK + c0];
        floatx4 b = *(const floatx4*)&T[(size_t)is_[sub][t+1] * KK + c0];
        float s0 = ss_[sub][t], s1 = ss_[sub][t+1];
        acc.x = fmaf(s0, a.x, acc.x); acc.y = fmaf(s0, a.y, acc.y);
        acc.z = fmaf(s0, a.z, acc.z); acc.w = fmaf(s0, a.w, acc.w);
        acc.x = fmaf(s1, b.x, acc.x); acc.y = fmaf(s1, b.y, acc.y);
        acc.z = fmaf(s1, b.z, acc.z); acc.w = fmaf(s1, b.w, acc.w);
    }
    for (; t < Ls; ++t){
        floatx4 a = *(const floatx4*)&T[(size_t)is_[sub][t] * KK + c0];
        float s0 = ss_[sub][t];
        acc.x = fmaf(s0, a.x, acc.x); acc.y = fmaf(s0, a.y, acc.y);
        acc.z = fmaf(s0, a.z, acc.z); acc.w = fmaf(s0, a.w, acc.w);
    }
    for (t = Ls; t < L; ++t){            // overflow fallback
        floatx4 a = *(const floatx4*)&T[(size_t)isd[lo + t] * KK + c0];
        float s0 = ssd[lo + t];
        acc.x = fmaf(s0, a.x, acc.x); acc.y = fmaf(s0, a.y, acc.y);
        acc.z = fmaf(s0, a.z, acc.z); acc.w = fmaf(s0, a.w, acc.w);
    }
    if (r - c0 >= 0 && r - c0 < 4){      // zero the diagonal element
        if (r - c0 == 0) acc.x = 0.f;
        else if (r - c0 == 1) acc.y = 0.f;
        else if (r - c0 == 2) acc.z = 0.f;
        else acc.w = 0.f;
    }
    __builtin_nontemporal_store(acc, (floatx4*)&Ac[(size_t)r * KK + c0]);
}

// ---------------- fallback: edge-pair outer products with global atomics ----------------
__global__ void ac_kernel(const int* e_src, const int* e_dst, const float* ew,
                          const int* off_src,
                          const int* cp, const float* sp, float* Ac){
    int e1 = blockIdx.x * blockDim.x + threadIdx.x;
    if (e1 >= NE) return;
    int i = (e1 < E0S) ? e_src[e1] : e1 - E0S;
    int j = (e1 < E0S) ? e_dst[e1] : e1 - E0S;
    float w1 = (e1 < E0S) ? ew[e1] : 1.0f;
    int ilo = off_src[i], ihi = off_src[i+1];
    int jlo = off_src[j], jhi = off_src[j+1];
    for (int ta = ilo; ta < ihi; ++ta){
        int ca = cp[ta];
        if (ca < 0) continue;
        float va = sp[ta] * w1;
        float* rowp = Ac + (size_t)ca * KK;
        for (int tb = jlo; tb < jhi; ++tb){
            int cb = cp[tb];
            if (cb < 0) continue;
            atomicAdd(&rowp[cb], va * sp[tb]);
        }
    }
}

// ---------------- zero diagonal of A_c (fallback path) ----------------
__global__ void diag_kernel(float* Ac){
    int r = blockIdx.x * blockDim.x + threadIdx.x;
    if (r < KK) Ac[(size_t)r * KK + r] = 0.f;
}

extern "C" void kernel_launch(void* const* d_in, const int* in_sizes, int n_in,
                              void* d_out, int out_size, void* d_ws, size_t ws_size,
                              hipStream_t stream){
    const float* x     = (const float*)d_in[0];
    const int*   ei    = (const int*)d_in[1];
    const float* ew    = (const float*)d_in[2];
    const float* lin_w = (const float*)d_in[3];
    const float* lin_b = (const float*)d_in[4];
    const float* att_w = (const float*)d_in[5];
    const float* att_b = (const float*)d_in[6];
    const float* le1_w = (const float*)d_in[7];
    const float* le1_b = (const float*)d_in[8];
    const float* le2_w = (const float*)d_in[9];
    const float* le3_w = (const float*)d_in[10];
    const float* le3_b = (const float*)d_in[11];

    const int* e_src = ei;
    const int* e_dst = ei + E0S;

    float* out    = (float*)d_out;
    float* x_out  = out;                                     // KK*DD
    float* Ac     = out + (size_t)KK * DD;                   // KK*KK
    float* operm  = out + (size_t)KK * DD + (size_t)KK * KK; // KK

    // workspace carve-up (all 4-byte elements)
    char* wp = (char*)d_ws;
    auto alloc_i = [&](size_t n){ int* p = (int*)wp; wp += n * sizeof(int); return p; };
    auto alloc_f = [&](size_t n){ float* p = (float*)wp; wp += n * sizeof(float); return p; };

    int* deg_dst = alloc_i(NN);
    int* deg_src = alloc_i(NN);
    int* off_dst = alloc_i(NN + 1);
    int* off_src = alloc_i(NN + 1);
    int* cur_dst = alloc_i(NN);
    int* cur_src = alloc_i(NN);
    int* eid_dst = alloc_i(NE);
    int* eid_src = alloc_i(NE);
    int* colmap  = alloc_i(NN);
    int* perm    = alloc_i(KK);
    int* isd     = alloc_i(NE);    // src node per dst-CSR position
    int* cp      = alloc_i(NE);    // colmap[dst] per src-CSR position
    float* sp    = alloc_f(NE);    // sc per src-CSR position
    float* ssd   = alloc_f(NE);    // softmax score per dst-CSR position
    float* q_s   = alloc_f(NN);
    float* p_s   = alloc_f(NN);
    float* a_    = alloc_f(NN);
    float* b_    = alloc_f(NN);
    float* c_    = alloc_f(NN);
    float* fit   = alloc_f(NN);
    float* sc    = alloc_f(NE);
    float* xn    = alloc_f((size_t)NN * DD);
    float* T     = alloc_f((size_t)NN * KK);   // 32 MB dense intermediate for A_c
    bool dense_ok = ((size_t)(wp - (char*)d_ws) <= ws_size);
    (void)n_in; (void)in_sizes; (void)out_size;

    const int EB = (NE + 255) / 256;

    init_kernel<<<2048, 256, 0, stream>>>(deg_dst, deg_src, colmap, Ac, dense_ok ? 0 : 1);
    count_kernel<<<EB, 256, 0, stream>>>(e_src, e_dst, deg_dst, deg_src);
    scan_kernel<<<2, 1024, 0, stream>>>(deg_dst, off_dst, cur_dst, deg_src, off_src, cur_src);
    fill_kernel<<<EB, 256, 0, stream>>>(e_src, e_dst, cur_dst, cur_src, eid_dst, eid_src);
    segsort_kernel<<<(2 * NN) / 4, 256, 0, stream>>>(off_dst, eid_dst, off_src, eid_src, e_src, isd);
    sml_kernel<<<NN / LROWS, 256, 0, stream>>>(x, off_dst, isd, lin_w, lin_b, att_w, q_s, p_s);
    softxn_kernel<<<NN, 256, 0, stream>>>(x, off_dst, eid_dst, isd, q_s, p_s, att_b,
                                          le1_w, le1_b, le2_w, le3_w, le3_b,
                                          sc, ssd, xn, a_, b_, c_);
    fitness_kernel<<<NN / 4, 256, 0, stream>>>(off_dst, isd, a_, b_, c_, fit);
    topk_kernel<<<1, 1024, 0, stream>>>(fit, perm, colmap, operm);
    xoutprep_kernel<<<KK + EB, 256, 0, stream>>>(xn, fit, perm, x_out,
                                                 eid_src, e_dst, colmap, sc, cp, sp);
    if (dense_ok){
        spgemm1_kernel<<<NN, 256, 0, stream>>>(e_dst, ew, off_src, eid_src, cp, sp, T);
        spgemm2_kernel<<<dim3(8, 512), 256, 0, stream>>>(perm, off_dst, isd, ssd, T, Ac);
    } else {
        ac_kernel<<<EB, 256, 0, stream>>>(e_src, e_dst, ew, off_src, cp, sp, Ac);
        diag_kernel<<<(KK + 255) / 256, 256, 0, stream>>>(Ac);
    }
}

// Round 10
// 212.682 us; speedup vs baseline: 1.0891x; 1.0891x over previous
//
#include <hip/hip_runtime.h>
#include <cstdint>
#include <cstddef>
#include <math.h>

#define NN   4096
#define DD   256
#define E0S  131072
#define NE   (E0S + NN)     // 135168 edges incl. self loops
#define KK   2048
#define NEG_SLOPE 0.2f
#define SEGCAP 256          // max segment length staged in LDS

typedef float floatx4 __attribute__((ext_vector_type(4)));   // clang-native vec4

// edge accessors: e < E0S -> from input arrays; else self-loop (e - E0S)
__device__ __forceinline__ int esrc(const int* s, int e){ return e < E0S ? s[e] : e - E0S; }
__device__ __forceinline__ int edst(const int* d, int e){ return e < E0S ? d[e] : e - E0S; }

// ---------------- init: zero degree arrays, colmap=-1, (optionally) zero A_c ------------
__global__ void init_kernel(int* deg_dst, int* deg_src, int* colmap, float* Ac, int zero_ac){
    int i = blockIdx.x * blockDim.x + threadIdx.x;
    int stride = gridDim.x * blockDim.x;
    if (zero_ac){
        for (size_t t = i; t < (size_t)KK * KK; t += stride) Ac[t] = 0.f;
    }
    for (int t = i; t < NN; t += stride){ deg_dst[t] = 0; deg_src[t] = 0; colmap[t] = -1; }
}

// ---------------- degree count ----------------
__global__ void count_kernel(const int* e_src, const int* e_dst, int* deg_dst, int* deg_src){
    int e = blockIdx.x * blockDim.x + threadIdx.x;
    if (e < NE){
        atomicAdd(&deg_dst[edst(e_dst, e)], 1);
        atomicAdd(&deg_src[esrc(e_src, e)], 1);
    }
}

// ---------------- exclusive scan of degrees (one block per array) ----------------
__global__ void __launch_bounds__(1024) scan_kernel(const int* degA, int* offA, int* curA,
                                                    const int* degB, int* offB, int* curB){
    const int* deg = (blockIdx.x == 0) ? degA : degB;
    int* off = (blockIdx.x == 0) ? offA : offB;
    int* cur = (blockIdx.x == 0) ? curA : curB;
    __shared__ int part[1024];
    int t = threadIdx.x;
    int base = t * 4;
    int s0 = deg[base], s1 = deg[base+1], s2 = deg[base+2], s3 = deg[base+3];
    int tot = s0 + s1 + s2 + s3;
    part[t] = tot;
    __syncthreads();
    for (int d = 1; d < 1024; d <<= 1){
        int v = (t >= d) ? part[t - d] : 0;
        __syncthreads();
        part[t] += v;
        __syncthreads();
    }
    int excl = part[t] - tot;
    off[base]   = excl;            cur[base]   = excl;
    off[base+1] = excl + s0;       cur[base+1] = excl + s0;
    off[base+2] = excl + s0 + s1;  cur[base+2] = excl + s0 + s1;
    off[base+3] = excl + s0 + s1 + s2; cur[base+3] = excl + s0 + s1 + s2;
    if (t == 1023) off[NN] = part[1023];
}

// ---------------- CSR fill ----------------
__global__ void fill_kernel(const int* e_src, const int* e_dst, int* cur_dst, int* cur_src,
                            int* eid_dst, int* eid_src){
    int e = blockIdx.x * blockDim.x + threadIdx.x;
    if (e < NE){
        int p = atomicAdd(&cur_dst[edst(e_dst, e)], 1); eid_dst[p] = e;
        int q = atomicAdd(&cur_src[esrc(e_src, e)], 1); eid_src[q] = e;
    }
}

// ---------------- sort each CSR segment ascending (determinism): rank-by-count ----------
// also emits isd[u] = src node at dst-CSR position u
__global__ void segsort_kernel(const int* off_dst, int* eid_dst, const int* off_src, int* eid_src,
                               const int* e_src, int* isd){
    __shared__ int buf[4][SEGCAP];
    int wid  = (blockIdx.x * blockDim.x + threadIdx.x) >> 6;   // global wave id in [0, 2*NN)
    int lane = threadIdx.x & 63;
    int w    = threadIdx.x >> 6;
    const int* off; int* eid; int n; bool isdst;
    if (wid < NN){ off = off_dst; eid = eid_dst; n = wid; isdst = true; }
    else         { off = off_src; eid = eid_src; n = wid - NN; isdst = false; }
    int lo = off[n], hi = off[n+1];
    int L = hi - lo;
    int Lc = (L <= SEGCAP) ? L : SEGCAP;
    for (int i = lane; i < Lc; i += 64) buf[w][i] = eid[lo + i];
    __syncthreads();
    if (L <= SEGCAP){
        for (int i = lane; i < L; i += 64){
            int v = buf[w][i];
            int r = 0;
            for (int j = 0; j < L; ++j) r += (buf[w][j] < v);
            eid[lo + r] = v;
            if (isdst) isd[lo + r] = esrc(e_src, v);
        }
    } else if (lane == 0){
        // pathological fallback (never expected at this size)
        for (int i = lo + 1; i < hi; ++i){
            int v = eid[i]; int j = i - 1;
            while (j >= lo && eid[j] > v){ eid[j+1] = eid[j]; --j; }
            eid[j+1] = v;
        }
        if (isdst) for (int i = lo; i < hi; ++i) isd[i] = esrc(e_src, eid[i]);
    }
}

// ---------------- x_q = segment_max(x[src], dst): 4 nodes/block, 64 lanes/node, vec4 -----
__global__ void segmax_kernel(const float* x, const int* off, const int* isd, float* x_q){
    __shared__ int is_[4][SEGCAP];
    int g = threadIdx.x >> 6;          // node subgroup 0..3
    int l = threadIdx.x & 63;          // lane within group
    int n = blockIdx.x * 4 + g;
    int lo = off[n], hi = off[n+1];
    int L = hi - lo;
    int Ls = (L <= SEGCAP) ? L : SEGCAP;
    for (int t = l; t < Ls; t += 64) is_[g][t] = isd[lo + t];
    __syncthreads();
    int c0 = l * 4;                    // 4 consecutive columns per thread
    floatx4 m = {-INFINITY, -INFINITY, -INFINITY, -INFINITY};
    int t = 0;
    for (; t + 1 < Ls; t += 2){
        floatx4 v0 = *(const floatx4*)&x[(size_t)is_[g][t]   * DD + c0];
        floatx4 v1 = *(const floatx4*)&x[(size_t)is_[g][t+1] * DD + c0];
        m.x = fmaxf(m.x, fmaxf(v0.x, v1.x));
        m.y = fmaxf(m.y, fmaxf(v0.y, v1.y));
        m.z = fmaxf(m.z, fmaxf(v0.z, v1.z));
        m.w = fmaxf(m.w, fmaxf(v0.w, v1.w));
    }
    if (t < Ls){
        floatx4 v0 = *(const floatx4*)&x[(size_t)is_[g][t] * DD + c0];
        m.x = fmaxf(m.x, v0.x); m.y = fmaxf(m.y, v0.y);
        m.z = fmaxf(m.z, v0.z); m.w = fmaxf(m.w, v0.w);
    }
    for (t = Ls; t < L; ++t){          // overflow fallback
        floatx4 v0 = *(const floatx4*)&x[(size_t)isd[lo + t] * DD + c0];
        m.x = fmaxf(m.x, v0.x); m.y = fmaxf(m.y, v0.y);
        m.z = fmaxf(m.z, v0.z); m.w = fmaxf(m.w, v0.w);
    }
    *(floatx4*)&x_q[(size_t)n * DD + c0] = m;
}

// ---------------- fused: lin (x_q @ lin_w + b) -> attention dots (4 nodes/block) ---------
// FMA order per output element identical to old lin_kernel (bc, then k ascending);
// reduction tree identical to old nodedots_kernel -> bit-identical q_s/p_s.
#define LR2 4
__global__ void linnd_kernel(const float* x, const float* x_q,
                             const float* lin_w, const float* lin_b, const float* att_w,
                             float* q_s, float* p_s){
    __shared__ float xs[LR2][DD];
    __shared__ float s1[256], s2[256];
    int col = threadIdx.x;
    int r0 = blockIdx.x * LR2;
    for (int r = 0; r < LR2; ++r) xs[r][col] = x_q[(size_t)(r0 + r) * DD + col];
    __syncthreads();
    float acc[LR2];
    float bc = lin_b[col];
    #pragma unroll
    for (int r = 0; r < LR2; ++r) acc[r] = bc;
    for (int kk = 0; kk < DD; ++kk){
        float wv = lin_w[(size_t)kk * DD + col];
        #pragma unroll
        for (int r = 0; r < LR2; ++r) acc[r] = fmaf(xs[r][kk], wv, acc[r]);
    }
    float aw1 = att_w[col];
    float aw2 = att_w[DD + col];
    for (int r = 0; r < LR2; ++r){
        int n = r0 + r;
        s1[col] = acc[r] * aw1;
        s2[col] = x[(size_t)n * DD + col] * aw2;
        __syncthreads();
        for (int d = 128; d > 0; d >>= 1){
            if (col < d){ s1[col] += s1[col + d]; s2[col] += s2[col + d]; }
            __syncthreads();
        }
        if (col == 0){ q_s[n] = s1[0]; p_s[n] = s2[0]; }
        __syncthreads();
    }
}

// ---------------- fused: per-dst softmax -> xn segment-sum -> LEConv dots (1 node/block) --
__global__ void softxn_kernel(const float* x, const int* off, const int* eid, const int* isd,
                              const float* q_s, const float* p_s, const float* att_b,
                              const float* le1_w, const float* le1_b, const float* le2_w,
                              const float* le3_w, const float* le3_b,
                              float* sc, float* ssd, float* xn,
                              float* a_, float* b_, float* c_){
    __shared__ int   is_[SEGCAP];
    __shared__ float ss_[SEGCAP];
    __shared__ float s1[256], s2[256], s3[256];
    int n = blockIdx.x, col = threadIdx.x;
    int lo = off[n], hi = off[n+1];
    int L = hi - lo;
    int Ls = (L <= SEGCAP) ? L : SEGCAP;
    for (int t = col; t < Ls; t += 256) is_[t] = isd[lo + t];
    __syncthreads();
    if (col < 64){
        int lane = col;
        float ab = att_b[0];
        float qn = q_s[n];
        float m = -INFINITY;
        for (int t = lane; t < L; t += 64){
            int sn = (t < Ls) ? is_[t] : isd[lo + t];
            float s = qn + p_s[sn] + ab;
            s = (s > 0.f) ? s : NEG_SLOPE * s;
            m = fmaxf(m, s);
        }
        #pragma unroll
        for (int d = 32; d > 0; d >>= 1) m = fmaxf(m, __shfl_xor(m, d));
        float sum = 0.f;
        for (int t = lane; t < L; t += 64){
            int sn = (t < Ls) ? is_[t] : isd[lo + t];
            float s = qn + p_s[sn] + ab;
            s = (s > 0.f) ? s : NEG_SLOPE * s;
            float ex = expf(s - m);
            if (t < Ls) ss_[t] = ex; else ssd[lo + t] = ex;
            sum += ex;
        }
        #pragma unroll
        for (int d = 32; d > 0; d >>= 1) sum += __shfl_xor(sum, d);
        float inv = 1.f / sum;
        for (int t = lane; t < L; t += 64){
            float v = ((t < Ls) ? ss_[t] : ssd[lo + t]) * inv;
            if (t < Ls) ss_[t] = v;
            ssd[lo + t] = v;          // position-indexed (spgemm2)
            sc[eid[lo + t]] = v;      // edge-indexed (prepsrc)
        }
    }
    __syncthreads();
    // xn accumulation (identical order to old xnfit_kernel)
    float acc = 0.f;
    int t = 0;
    for (; t + 1 < Ls; t += 2){
        float v0 = x[(size_t)is_[t]   * DD + col];
        float v1 = x[(size_t)is_[t+1] * DD + col];
        acc = fmaf(ss_[t],   v0, acc);
        acc = fmaf(ss_[t+1], v1, acc);
    }
    if (t < Ls) acc = fmaf(ss_[t], x[(size_t)is_[t] * DD + col], acc);
    for (t = Ls; t < L; ++t)             // overflow fallback
        acc = fmaf(ssd[lo + t], x[(size_t)isd[lo + t] * DD + col], acc);
    xn[(size_t)n * DD + col] = acc;
    // fused LEConv dots (same tree reduction -> identical numerics)
    s1[col] = acc * le1_w[col];
    s2[col] = acc * le2_w[col];
    s3[col] = acc * le3_w[col];
    __syncthreads();
    for (int dd = 128; dd > 0; dd >>= 1){
        if (col < dd){ s1[col] += s1[col+dd]; s2[col] += s2[col+dd]; s3[col] += s3[col+dd]; }
        __syncthreads();
    }
    if (col == 0){
        a_[n] = s1[0] + le1_b[0];
        b_[n] = s2[0];
        c_[n] = s3[0] + le3_b[0];
    }
}

// ---------------- fitness = sigmoid(segsum(a[src]-b[dst]) + c) (one wave per node) --------
__global__ void fitness_kernel(const int* off, const int* isd,
                               const float* a_, const float* b_, const float* c_,
                               float* fit){
    int wave = threadIdx.x >> 6;
    int lane = threadIdx.x & 63;
    int n = blockIdx.x * 4 + wave;
    int lo = off[n], hi = off[n+1];
    float bn = b_[n];
    float s = 0.f;
    for (int t = lo + lane; t < hi; t += 64){
        s += a_[isd[t]] - bn;
    }
    #pragma unroll
    for (int d = 32; d > 0; d >>= 1) s += __shfl_xor(s, d);
    if (lane == 0){
        float z = s + c_[n];
        fit[n] = 1.f / (1.f + expf(-z));
    }
}

// ---------------- top-k via bitonic sort of (value desc, idx asc) keys ----------------
__global__ void __launch_bounds__(1024) topk_kernel(const float* fit, int* perm, int* colmap,
                                                    float* out_perm){
    __shared__ unsigned long long keys[NN];
    int t = threadIdx.x;
    for (int i = t; i < NN; i += 1024){
        unsigned int u = __float_as_uint(fit[i]);
        u = (u & 0x80000000u) ? ~u : (u | 0x80000000u);  // monotone map
        u = ~u;                                           // descending
        keys[i] = ((unsigned long long)u << 32) | (unsigned int)i;
    }
    __syncthreads();
    for (unsigned int ssize = 2; ssize <= NN; ssize <<= 1){
        for (unsigned int stride = ssize >> 1; stride > 0; stride >>= 1){
            for (int i = t; i < NN / 2; i += 1024){
                unsigned int idx = 2u * i - (i & (stride - 1u));
                unsigned int par = idx + stride;
                bool asc = ((idx & ssize) == 0u);
                unsigned long long a = keys[idx], b = keys[par];
                if ((a > b) == asc){ keys[idx] = b; keys[par] = a; }
            }
            __syncthreads();
        }
    }
    for (int i = t; i < KK; i += 1024){
        int node = (int)(keys[i] & 0xFFFFFFFFull);
        perm[i] = node;
        colmap[node] = i;
        out_perm[i] = (float)node;
    }
}

// ---------------- fused: x_out gather + src-side prep (cp/sp) ----------------
__global__ void xoutprep_kernel(const float* xn, const float* fit, const int* perm, float* x_out,
                                const int* eid_src, const int* e_dst, const int* colmap,
                                const float* sc, int* cp, float* sp){
    int b = blockIdx.x;
    if (b < KK){
        int r = b, d = threadIdx.x;
        int p = perm[r];
        x_out[(size_t)r * DD + d] = xn[(size_t)p * DD + d] * fit[p];
    } else {
        int u = (b - KK) * 256 + threadIdx.x;
        if (u < NE){
            int f = eid_src[u];
            cp[u] = colmap[edst(e_dst, f)];
            sp[u] = sc[f];
        }
    }
}

// ---------------- T[i,:] = sum over out-edges e=(i,j): w_e * Sp[j,:]  (row in LDS) -------
// 32-lane sub-waves: 8 segments in flight (deg~33 -> ~full lane utilization).
__global__ void spgemm1_kernel(const int* e_dst, const float* ew,
                               const int* off_src, const int* eid_src,
                               const int* cp, const float* sp, float* T){
    __shared__ float row[KK];
    __shared__ int   jlo_[SEGCAP];
    __shared__ int   jhi_[SEGCAP];
    __shared__ float w_[SEGCAP];
    int i = blockIdx.x;
    for (int c = threadIdx.x; c < KK; c += 256) row[c] = 0.f;
    int lo = off_src[i], hi = off_src[i+1];
    int L = hi - lo;
    int Ls = (L <= SEGCAP) ? L : SEGCAP;
    for (int t = threadIdx.x; t < Ls; t += 256){
        int e = eid_src[lo + t];
        int j = edst(e_dst, e);
        jlo_[t] = off_src[j];
        jhi_[t] = off_src[j+1];
        w_[t]   = (e < E0S) ? ew[e] : 1.0f;
    }
    __syncthreads();
    int sw = threadIdx.x >> 5, ln = threadIdx.x & 31;
    for (int t = sw; t < Ls; t += 8){
        float w1 = w_[t];
        for (int u = jlo_[t] + ln; u < jhi_[t]; u += 32){
            int c = cp[u];                       // contiguous stream
            if (c >= 0) atomicAdd(&row[c], w1 * sp[u]);
        }
    }
    for (int t = Ls + sw; t < L; t += 8){   // overflow fallback
        int e = eid_src[lo + t];
        int j = edst(e_dst, e);
        float w1 = (e < E0S) ? ew[e] : 1.0f;
        int jlo = off_src[j], jhi = off_src[j+1];
        for (int u = jlo + ln; u < jhi; u += 32){
            int c = cp[u];
            if (c >= 0) atomicAdd(&row[c], w1 * sp[u]);
        }
    }
    __syncthreads();
    float* Trow = T + (size_t)i * KK;
    for (int c = threadIdx.x; c < KK; c += 256) Trow[c] = row[c];
}

// ---------------- A_c[r, chunk] = sum over dst-positions of perm[r]: ssd * T[isd, chunk] ----
// 16 chunks of 128 cols (2 MB T-slice << 4 MB XCD L2). grid dim3(8, 512), 256 thr:
// chunk = bx + 8*(by>>8) -> linear id % 8 = bx pins each chunk's slice to one XCD.
// Each block: 8 rows (32 lanes/row), floatx4 (4 cols) per thread. Nontemporal Ac store.
__global__ void spgemm2_kernel(const int* perm, const int* off_dst,
                               const int* isd, const float* ssd,
                               const float* T, float* Ac){
    __shared__ int   is_[8][SEGCAP];
    __shared__ float ss_[8][SEGCAP];
    int bx = blockIdx.x;              // 0..7
    int by = blockIdx.y;              // 0..511
    int half = by >> 8;               // 0 or 1
    int rr   = by & 255;              // 0..255
    int sub  = threadIdx.x >> 5;      // 0..7 (row within block)
    int lane = threadIdx.x & 31;      // 0..31
    int r = rr * 8 + sub;
    int chunk = bx + 8 * half;        // 0..15
    int c0 = chunk * 128 + lane * 4;  // 4 consecutive columns per thread
    int node = perm[r];
    int lo = off_dst[node], hi = off_dst[node+1];
    int L = hi - lo;
    int Ls = (L <= SEGCAP) ? L : SEGCAP;
    for (int t = lane; t < Ls; t += 32){
        is_[sub][t] = isd[lo + t];
        ss_[sub][t] = ssd[lo + t];
    }
    __syncthreads();
    floatx4 acc = {0.f, 0.f, 0.f, 0.f};
    int t = 0;
    for (; t + 1 < Ls; t += 2){
        floatx4 a = *(const floatx4*)&T[(size_t)is_[sub][t]   * KK + c0];
        floatx4 b = *(const floatx4*)&T[(size_t)is_[sub][t+1] * KK + c0];
        float s0 = ss_[sub][t], s1 = ss_[sub][t+1];
        acc.x = fmaf(s0, a.x, acc.x); acc.y = fmaf(s0, a.y, acc.y);
        acc.z = fmaf(s0, a.z, acc.z); acc.w = fmaf(s0, a.w, acc.w);
        acc.x = fmaf(s1, b.x, acc.x); acc.y = fmaf(s1, b.y, acc.y);
        acc.z = fmaf(s1, b.z, acc.z); acc.w = fmaf(s1, b.w, acc.w);
    }
    for (; t < Ls; ++t){
        floatx4 a = *(const floatx4*)&T[(size_t)is_[sub][t] * KK + c0];
        float s0 = ss_[sub][t];
        acc.x = fmaf(s0, a.x, acc.x); acc.y = fmaf(s0, a.y, acc.y);
        acc.z = fmaf(s0, a.z, acc.z); acc.w = fmaf(s0, a.w, acc.w);
    }
    for (t = Ls; t < L; ++t){            // overflow fallback
        floatx4 a = *(const floatx4*)&T[(size_t)isd[lo + t] * KK + c0];
        float s0 = ssd[lo + t];
        acc.x = fmaf(s0, a.x, acc.x); acc.y = fmaf(s0, a.y, acc.y);
        acc.z = fmaf(s0, a.z, acc.z); acc.w = fmaf(s0, a.w, acc.w);
    }
    if (r - c0 >= 0 && r - c0 < 4){      // zero the diagonal element
        if (r - c0 == 0) acc.x = 0.f;
        else if (r - c0 == 1) acc.y = 0.f;
        else if (r - c0 == 2) acc.z = 0.f;
        else acc.w = 0.f;
    }
    __builtin_nontemporal_store(acc, (floatx4*)&Ac[(size_t)r * KK + c0]);
}

// ---------------- fallback: edge-pair outer products with global atomics ----------------
__global__ void ac_kernel(const int* e_src, const int* e_dst, const float* ew,
                          const int* off_src,
                          const int* cp, const float* sp, float* Ac){
    int e1 = blockIdx.x * blockDim.x + threadIdx.x;
    if (e1 >= NE) return;
    int i = (e1 < E0S) ? e_src[e1] : e1 - E0S;
    int j = (e1 < E0S) ? e_dst[e1] : e1 - E0S;
    float w1 = (e1 < E0S) ? ew[e1] : 1.0f;
    int ilo = off_src[i], ihi = off_src[i+1];
    int jlo = off_src[j], jhi = off_src[j+1];
    for (int ta = ilo; ta < ihi; ++ta){
        int ca = cp[ta];
        if (ca < 0) continue;
        float va = sp[ta] * w1;
        float* rowp = Ac + (size_t)ca * KK;
        for (int tb = jlo; tb < jhi; ++tb){
            int cb = cp[tb];
            if (cb < 0) continue;
            atomicAdd(&rowp[cb], va * sp[tb]);
        }
    }
}

// ---------------- zero diagonal of A_c (fallback path) ----------------
__global__ void diag_kernel(float* Ac){
    int r = blockIdx.x * blockDim.x + threadIdx.x;
    if (r < KK) Ac[(size_t)r * KK + r] = 0.f;
}

extern "C" void kernel_launch(void* const* d_in, const int* in_sizes, int n_in,
                              void* d_out, int out_size, void* d_ws, size_t ws_size,
                              hipStream_t stream){
    const float* x     = (const float*)d_in[0];
    const int*   ei    = (const int*)d_in[1];
    const float* ew    = (const float*)d_in[2];
    const float* lin_w = (const float*)d_in[3];
    const float* lin_b = (const float*)d_in[4];
    const float* att_w = (const float*)d_in[5];
    const float* att_b = (const float*)d_in[6];
    const float* le1_w = (const float*)d_in[7];
    const float* le1_b = (const float*)d_in[8];
    const float* le2_w = (const float*)d_in[9];
    const float* le3_w = (const float*)d_in[10];
    const float* le3_b = (const float*)d_in[11];

    const int* e_src = ei;
    const int* e_dst = ei + E0S;

    float* out    = (float*)d_out;
    float* x_out  = out;                                     // KK*DD
    float* Ac     = out + (size_t)KK * DD;                   // KK*KK
    float* operm  = out + (size_t)KK * DD + (size_t)KK * KK; // KK

    // workspace carve-up (all 4-byte elements)
    char* wp = (char*)d_ws;
    auto alloc_i = [&](size_t n){ int* p = (int*)wp; wp += n * sizeof(int); return p; };
    auto alloc_f = [&](size_t n){ float* p = (float*)wp; wp += n * sizeof(float); return p; };

    int* deg_dst = alloc_i(NN);
    int* deg_src = alloc_i(NN);
    int* off_dst = alloc_i(NN + 1);
    int* off_src = alloc_i(NN + 1);
    int* cur_dst = alloc_i(NN);
    int* cur_src = alloc_i(NN);
    int* eid_dst = alloc_i(NE);
    int* eid_src = alloc_i(NE);
    int* colmap  = alloc_i(NN);
    int* perm    = alloc_i(KK);
    int* isd     = alloc_i(NE);    // src node per dst-CSR position
    int* cp      = alloc_i(NE);    // colmap[dst] per src-CSR position
    float* sp    = alloc_f(NE);    // sc per src-CSR position
    float* ssd   = alloc_f(NE);    // softmax score per dst-CSR position
    float* q_s   = alloc_f(NN);
    float* p_s   = alloc_f(NN);
    float* a_    = alloc_f(NN);
    float* b_    = alloc_f(NN);
    float* c_    = alloc_f(NN);
    float* fit   = alloc_f(NN);
    float* sc    = alloc_f(NE);
    float* x_q   = alloc_f((size_t)NN * DD);
    float* xn    = alloc_f((size_t)NN * DD);
    float* T     = alloc_f((size_t)NN * KK);   // 32 MB dense intermediate for A_c
    bool dense_ok = ((size_t)(wp - (char*)d_ws) <= ws_size);
    (void)n_in; (void)in_sizes; (void)out_size;

    const int EB = (NE + 255) / 256;

    init_kernel<<<2048, 256, 0, stream>>>(deg_dst, deg_src, colmap, Ac, dense_ok ? 0 : 1);
    count_kernel<<<EB, 256, 0, stream>>>(e_src, e_dst, deg_dst, deg_src);
    scan_kernel<<<2, 1024, 0, stream>>>(deg_dst, off_dst, cur_dst, deg_src, off_src, cur_src);
    fill_kernel<<<EB, 256, 0, stream>>>(e_src, e_dst, cur_dst, cur_src, eid_dst, eid_src);
    segsort_kernel<<<(2 * NN) / 4, 256, 0, stream>>>(off_dst, eid_dst, off_src, eid_src, e_src, isd);
    segmax_kernel<<<NN / 4, 256, 0, stream>>>(x, off_dst, isd, x_q);
    linnd_kernel<<<NN / LR2, 256, 0, stream>>>(x, x_q, lin_w, lin_b, att_w, q_s, p_s);
    softxn_kernel<<<NN, 256, 0, stream>>>(x, off_dst, eid_dst, isd, q_s, p_s, att_b,
                                          le1_w, le1_b, le2_w, le3_w, le3_b,
                                          sc, ssd, xn, a_, b_, c_);
    fitness_kernel<<<NN / 4, 256, 0, stream>>>(off_dst, isd, a_, b_, c_, fit);
    topk_kernel<<<1, 1024, 0, stream>>>(fit, perm, colmap, operm);
    xoutprep_kernel<<<KK + EB, 256, 0, stream>>>(xn, fit, perm, x_out,
                                                 eid_src, e_dst, colmap, sc, cp, sp);
    if (dense_ok){
        spgemm1_kernel<<<NN, 256, 0, stream>>>(e_dst, ew, off_src, eid_src, cp, sp, T);
        spgemm2_kernel<<<dim3(8, 512), 256, 0, stream>>>(perm, off_dst, isd, ssd, T, Ac);
    } else {
        ac_kernel<<<EB, 256, 0, stream>>>(e_src, e_dst, ew, off_src, cp, sp, Ac);
        diag_kernel<<<(KK + 255) / 256, 256, 0, stream>>>(Ac);
    }
}

// Round 11
// 204.499 us; speedup vs baseline: 1.1327x; 1.0400x over previous
//
#include <hip/hip_runtime.h>
#include <cstdint>
#include <cstddef>
#include <math.h>

#define NN   4096
#define DD   256
#define E0S  131072
#define NE   (E0S + NN)     // 135168 edges incl. self loops
#define KK   2048
#define NEG_SLOPE 0.2f
#define SEGCAP 256          // max segment length staged in LDS

typedef float floatx4 __attribute__((ext_vector_type(4)));   // clang-native vec4

// edge accessors: e < E0S -> from input arrays; else self-loop (e - E0S)
__device__ __forceinline__ int esrc(const int* s, int e){ return e < E0S ? s[e] : e - E0S; }
__device__ __forceinline__ int edst(const int* d, int e){ return e < E0S ? d[e] : e - E0S; }

// ---------------- init: zero degree arrays, colmap=-1, (optionally) zero A_c ------------
__global__ void init_kernel(int* deg_dst, int* deg_src, int* colmap, float* Ac, int zero_ac){
    int i = blockIdx.x * blockDim.x + threadIdx.x;
    int stride = gridDim.x * blockDim.x;
    if (zero_ac){
        for (size_t t = i; t < (size_t)KK * KK; t += stride) Ac[t] = 0.f;
    }
    for (int t = i; t < NN; t += stride){ deg_dst[t] = 0; deg_src[t] = 0; colmap[t] = -1; }
}

// ---------------- degree count ----------------
__global__ void count_kernel(const int* e_src, const int* e_dst, int* deg_dst, int* deg_src){
    int e = blockIdx.x * blockDim.x + threadIdx.x;
    if (e < NE){
        atomicAdd(&deg_dst[edst(e_dst, e)], 1);
        atomicAdd(&deg_src[esrc(e_src, e)], 1);
    }
}

// ---------------- exclusive scan of degrees (one block per array) ----------------
__global__ void __launch_bounds__(1024) scan_kernel(const int* degA, int* offA, int* curA,
                                                    const int* degB, int* offB, int* curB){
    const int* deg = (blockIdx.x == 0) ? degA : degB;
    int* off = (blockIdx.x == 0) ? offA : offB;
    int* cur = (blockIdx.x == 0) ? curA : curB;
    __shared__ int part[1024];
    int t = threadIdx.x;
    int base = t * 4;
    int s0 = deg[base], s1 = deg[base+1], s2 = deg[base+2], s3 = deg[base+3];
    int tot = s0 + s1 + s2 + s3;
    part[t] = tot;
    __syncthreads();
    for (int d = 1; d < 1024; d <<= 1){
        int v = (t >= d) ? part[t - d] : 0;
        __syncthreads();
        part[t] += v;
        __syncthreads();
    }
    int excl = part[t] - tot;
    off[base]   = excl;            cur[base]   = excl;
    off[base+1] = excl + s0;       cur[base+1] = excl + s0;
    off[base+2] = excl + s0 + s1;  cur[base+2] = excl + s0 + s1;
    off[base+3] = excl + s0 + s1 + s2; cur[base+3] = excl + s0 + s1 + s2;
    if (t == 1023) off[NN] = part[1023];
}

// ---------------- CSR fill ----------------
__global__ void fill_kernel(const int* e_src, const int* e_dst, int* cur_dst, int* cur_src,
                            int* eid_dst, int* eid_src){
    int e = blockIdx.x * blockDim.x + threadIdx.x;
    if (e < NE){
        int p = atomicAdd(&cur_dst[edst(e_dst, e)], 1); eid_dst[p] = e;
        int q = atomicAdd(&cur_src[esrc(e_src, e)], 1); eid_src[q] = e;
    }
}

// ---------------- sort each CSR segment ascending (determinism): rank-by-count ----------
// also emits isd[u] = src node at dst-CSR position u
__global__ void segsort_kernel(const int* off_dst, int* eid_dst, const int* off_src, int* eid_src,
                               const int* e_src, int* isd){
    __shared__ int buf[4][SEGCAP];
    int wid  = (blockIdx.x * blockDim.x + threadIdx.x) >> 6;   // global wave id in [0, 2*NN)
    int lane = threadIdx.x & 63;
    int w    = threadIdx.x >> 6;
    const int* off; int* eid; int n; bool isdst;
    if (wid < NN){ off = off_dst; eid = eid_dst; n = wid; isdst = true; }
    else         { off = off_src; eid = eid_src; n = wid - NN; isdst = false; }
    int lo = off[n], hi = off[n+1];
    int L = hi - lo;
    int Lc = (L <= SEGCAP) ? L : SEGCAP;
    for (int i = lane; i < Lc; i += 64) buf[w][i] = eid[lo + i];
    __syncthreads();
    if (L <= SEGCAP){
        for (int i = lane; i < L; i += 64){
            int v = buf[w][i];
            int r = 0;
            for (int j = 0; j < L; ++j) r += (buf[w][j] < v);
            eid[lo + r] = v;
            if (isdst) isd[lo + r] = esrc(e_src, v);
        }
    } else if (lane == 0){
        // pathological fallback (never expected at this size)
        for (int i = lo + 1; i < hi; ++i){
            int v = eid[i]; int j = i - 1;
            while (j >= lo && eid[j] > v){ eid[j+1] = eid[j]; --j; }
            eid[j+1] = v;
        }
        if (isdst) for (int i = lo; i < hi; ++i) isd[i] = esrc(e_src, eid[i]);
    }
}

// ---------------- x_q = segment_max(x[src], dst): 4 nodes/block, 64 lanes/node, vec4 -----
__global__ void segmax_kernel(const float* x, const int* off, const int* isd, float* x_q){
    __shared__ int is_[4][SEGCAP];
    int g = threadIdx.x >> 6;          // node subgroup 0..3
    int l = threadIdx.x & 63;          // lane within group
    int n = blockIdx.x * 4 + g;
    int lo = off[n], hi = off[n+1];
    int L = hi - lo;
    int Ls = (L <= SEGCAP) ? L : SEGCAP;
    for (int t = l; t < Ls; t += 64) is_[g][t] = isd[lo + t];
    __syncthreads();
    int c0 = l * 4;                    // 4 consecutive columns per thread
    floatx4 m = {-INFINITY, -INFINITY, -INFINITY, -INFINITY};
    int t = 0;
    for (; t + 1 < Ls; t += 2){
        floatx4 v0 = *(const floatx4*)&x[(size_t)is_[g][t]   * DD + c0];
        floatx4 v1 = *(const floatx4*)&x[(size_t)is_[g][t+1] * DD + c0];
        m.x = fmaxf(m.x, fmaxf(v0.x, v1.x));
        m.y = fmaxf(m.y, fmaxf(v0.y, v1.y));
        m.z = fmaxf(m.z, fmaxf(v0.z, v1.z));
        m.w = fmaxf(m.w, fmaxf(v0.w, v1.w));
    }
    if (t < Ls){
        floatx4 v0 = *(const floatx4*)&x[(size_t)is_[g][t] * DD + c0];
        m.x = fmaxf(m.x, v0.x); m.y = fmaxf(m.y, v0.y);
        m.z = fmaxf(m.z, v0.z); m.w = fmaxf(m.w, v0.w);
    }
    for (t = Ls; t < L; ++t){          // overflow fallback
        floatx4 v0 = *(const floatx4*)&x[(size_t)isd[lo + t] * DD + c0];
        m.x = fmaxf(m.x, v0.x); m.y = fmaxf(m.y, v0.y);
        m.z = fmaxf(m.z, v0.z); m.w = fmaxf(m.w, v0.w);
    }
    *(floatx4*)&x_q[(size_t)n * DD + c0] = m;
}

// ---------------- fused: lin (x_q @ lin_w + b) -> attention dots (4 nodes/block) ---------
// FMA order per output element identical to old lin_kernel (bc, then k ascending);
// reduction tree identical to old nodedots_kernel -> bit-identical q_s/p_s.
#define LR2 4
__global__ void linnd_kernel(const float* x, const float* x_q,
                             const float* lin_w, const float* lin_b, const float* att_w,
                             float* q_s, float* p_s){
    __shared__ float xs[LR2][DD];
    __shared__ float s1[256], s2[256];
    int col = threadIdx.x;
    int r0 = blockIdx.x * LR2;
    for (int r = 0; r < LR2; ++r) xs[r][col] = x_q[(size_t)(r0 + r) * DD + col];
    __syncthreads();
    float acc[LR2];
    float bc = lin_b[col];
    #pragma unroll
    for (int r = 0; r < LR2; ++r) acc[r] = bc;
    for (int kk = 0; kk < DD; ++kk){
        float wv = lin_w[(size_t)kk * DD + col];
        #pragma unroll
        for (int r = 0; r < LR2; ++r) acc[r] = fmaf(xs[r][kk], wv, acc[r]);
    }
    float aw1 = att_w[col];
    float aw2 = att_w[DD + col];
    for (int r = 0; r < LR2; ++r){
        int n = r0 + r;
        s1[col] = acc[r] * aw1;
        s2[col] = x[(size_t)n * DD + col] * aw2;
        __syncthreads();
        for (int d = 128; d > 0; d >>= 1){
            if (col < d){ s1[col] += s1[col + d]; s2[col] += s2[col + d]; }
            __syncthreads();
        }
        if (col == 0){ q_s[n] = s1[0]; p_s[n] = s2[0]; }
        __syncthreads();
    }
}

// ---------------- fused: per-dst softmax -> xn -> LEConv dots (4 nodes/block, 1 wave each)
// Softmax: verbatim 64-lane code per wave. xn: floatx4, per-column order = t ascending
// (identical). LEConv dots: shfl_xor tree replicating the old 256-wide LDS tree pairings
// exactly (d=128->xor32, 64->16, 32->8, 16->4, 8->2, 4->1, then 4-elem register tree)
// -> bit-identical a_/b_/c_.
__global__ void softxn_kernel(const float* x, const int* off, const int* eid, const int* isd,
                              const float* q_s, const float* p_s, const float* att_b,
                              const float* le1_w, const float* le1_b, const float* le2_w,
                              const float* le3_w, const float* le3_b,
                              float* sc, float* ssd, float* xn,
                              float* a_, float* b_, float* c_){
    __shared__ int   is_[4][SEGCAP];
    __shared__ float ss_[4][SEGCAP];
    int g = threadIdx.x >> 6;          // node subgroup (== wave) 0..3
    int l = threadIdx.x & 63;          // lane within wave
    int n = blockIdx.x * 4 + g;
    int lo = off[n], hi = off[n+1];
    int L = hi - lo;
    int Ls = (L <= SEGCAP) ? L : SEGCAP;
    for (int t = l; t < Ls; t += 64) is_[g][t] = isd[lo + t];
    __syncthreads();
    // ---- softmax (verbatim old 64-lane code, one wave per node) ----
    {
        float ab = att_b[0];
        float qn = q_s[n];
        float m = -INFINITY;
        for (int t = l; t < L; t += 64){
            int sn = (t < Ls) ? is_[g][t] : isd[lo + t];
            float s = qn + p_s[sn] + ab;
            s = (s > 0.f) ? s : NEG_SLOPE * s;
            m = fmaxf(m, s);
        }
        #pragma unroll
        for (int d = 32; d > 0; d >>= 1) m = fmaxf(m, __shfl_xor(m, d));
        float sum = 0.f;
        for (int t = l; t < L; t += 64){
            int sn = (t < Ls) ? is_[g][t] : isd[lo + t];
            float s = qn + p_s[sn] + ab;
            s = (s > 0.f) ? s : NEG_SLOPE * s;
            float ex = expf(s - m);
            if (t < Ls) ss_[g][t] = ex; else ssd[lo + t] = ex;
            sum += ex;
        }
        #pragma unroll
        for (int d = 32; d > 0; d >>= 1) sum += __shfl_xor(sum, d);
        float inv = 1.f / sum;
        for (int t = l; t < L; t += 64){
            float v = ((t < Ls) ? ss_[g][t] : ssd[lo + t]) * inv;
            if (t < Ls) ss_[g][t] = v;
            ssd[lo + t] = v;          // position-indexed (spgemm2)
            sc[eid[lo + t]] = v;      // edge-indexed (prepsrc)
        }
    }
    __syncthreads();
    // ---- xn accumulation: 4 cols/lane, per-column order = t ascending (identical) ----
    int c0 = l * 4;
    floatx4 acc = {0.f, 0.f, 0.f, 0.f};
    int t = 0;
    for (; t + 1 < Ls; t += 2){
        floatx4 v0 = *(const floatx4*)&x[(size_t)is_[g][t]   * DD + c0];
        floatx4 v1 = *(const floatx4*)&x[(size_t)is_[g][t+1] * DD + c0];
        float s0 = ss_[g][t], s1 = ss_[g][t+1];
        acc.x = fmaf(s0, v0.x, acc.x); acc.y = fmaf(s0, v0.y, acc.y);
        acc.z = fmaf(s0, v0.z, acc.z); acc.w = fmaf(s0, v0.w, acc.w);
        acc.x = fmaf(s1, v1.x, acc.x); acc.y = fmaf(s1, v1.y, acc.y);
        acc.z = fmaf(s1, v1.z, acc.z); acc.w = fmaf(s1, v1.w, acc.w);
    }
    if (t < Ls){
        floatx4 v0 = *(const floatx4*)&x[(size_t)is_[g][t] * DD + c0];
        float s0 = ss_[g][t];
        acc.x = fmaf(s0, v0.x, acc.x); acc.y = fmaf(s0, v0.y, acc.y);
        acc.z = fmaf(s0, v0.z, acc.z); acc.w = fmaf(s0, v0.w, acc.w);
    }
    for (t = Ls; t < L; ++t){            // overflow fallback
        floatx4 v0 = *(const floatx4*)&x[(size_t)isd[lo + t] * DD + c0];
        float s0 = ssd[lo + t];
        acc.x = fmaf(s0, v0.x, acc.x); acc.y = fmaf(s0, v0.y, acc.y);
        acc.z = fmaf(s0, v0.z, acc.z); acc.w = fmaf(s0, v0.w, acc.w);
    }
    *(floatx4*)&xn[(size_t)n * DD + c0] = acc;
    // ---- LEConv dots: replicate old tree exactly ----
    floatx4 w1 = *(const floatx4*)&le1_w[c0];
    floatx4 w2 = *(const floatx4*)&le2_w[c0];
    floatx4 w3 = *(const floatx4*)&le3_w[c0];
    floatx4 v1 = acc * w1;
    floatx4 v2 = acc * w2;
    floatx4 v3 = acc * w3;
    #pragma unroll
    for (int m = 32; m >= 1; m >>= 1){
        v1.x += __shfl_xor(v1.x, m); v1.y += __shfl_xor(v1.y, m);
        v1.z += __shfl_xor(v1.z, m); v1.w += __shfl_xor(v1.w, m);
        v2.x += __shfl_xor(v2.x, m); v2.y += __shfl_xor(v2.y, m);
        v2.z += __shfl_xor(v2.z, m); v2.w += __shfl_xor(v2.w, m);
        v3.x += __shfl_xor(v3.x, m); v3.y += __shfl_xor(v3.y, m);
        v3.z += __shfl_xor(v3.z, m); v3.w += __shfl_xor(v3.w, m);
    }
    if (l == 0){
        v1.x += v1.z; v1.y += v1.w; v1.x += v1.y;   // = old d=2 then d=1 steps
        v2.x += v2.z; v2.y += v2.w; v2.x += v2.y;
        v3.x += v3.z; v3.y += v3.w; v3.x += v3.y;
        a_[n] = v1.x + le1_b[0];
        b_[n] = v2.x;
        c_[n] = v3.x + le3_b[0];
    }
}

// ---------------- fitness = sigmoid(segsum(a[src]-b[dst]) + c) (one wave per node) --------
__global__ void fitness_kernel(const int* off, const int* isd,
                               const float* a_, const float* b_, const float* c_,
                               float* fit){
    int wave = threadIdx.x >> 6;
    int lane = threadIdx.x & 63;
    int n = blockIdx.x * 4 + wave;
    int lo = off[n], hi = off[n+1];
    float bn = b_[n];
    float s = 0.f;
    for (int t = lo + lane; t < hi; t += 64){
        s += a_[isd[t]] - bn;
    }
    #pragma unroll
    for (int d = 32; d > 0; d >>= 1) s += __shfl_xor(s, d);
    if (lane == 0){
        float z = s + c_[n];
        fit[n] = 1.f / (1.f + expf(-z));
    }
}

// ---------------- top-k via bitonic sort of (value desc, idx asc) keys ----------------
__global__ void __launch_bounds__(1024) topk_kernel(const float* fit, int* perm, int* colmap,
                                                    float* out_perm){
    __shared__ unsigned long long keys[NN];
    int t = threadIdx.x;
    for (int i = t; i < NN; i += 1024){
        unsigned int u = __float_as_uint(fit[i]);
        u = (u & 0x80000000u) ? ~u : (u | 0x80000000u);  // monotone map
        u = ~u;                                           // descending
        keys[i] = ((unsigned long long)u << 32) | (unsigned int)i;
    }
    __syncthreads();
    for (unsigned int ssize = 2; ssize <= NN; ssize <<= 1){
        for (unsigned int stride = ssize >> 1; stride > 0; stride >>= 1){
            for (int i = t; i < NN / 2; i += 1024){
                unsigned int idx = 2u * i - (i & (stride - 1u));
                unsigned int par = idx + stride;
                bool asc = ((idx & ssize) == 0u);
                unsigned long long a = keys[idx], b = keys[par];
                if ((a > b) == asc){ keys[idx] = b; keys[par] = a; }
            }
            __syncthreads();
        }
    }
    for (int i = t; i < KK; i += 1024){
        int node = (int)(keys[i] & 0xFFFFFFFFull);
        perm[i] = node;
        colmap[node] = i;
        out_perm[i] = (float)node;
    }
}

// ---------------- fused: x_out gather + src-side prep (cp/sp) ----------------
__global__ void xoutprep_kernel(const float* xn, const float* fit, const int* perm, float* x_out,
                                const int* eid_src, const int* e_dst, const int* colmap,
                                const float* sc, int* cp, float* sp){
    int b = blockIdx.x;
    if (b < KK){
        int r = b, d = threadIdx.x;
        int p = perm[r];
        x_out[(size_t)r * DD + d] = xn[(size_t)p * DD + d] * fit[p];
    } else {
        int u = (b - KK) * 256 + threadIdx.x;
        if (u < NE){
            int f = eid_src[u];
            cp[u] = colmap[edst(e_dst, f)];
            sp[u] = sc[f];
        }
    }
}

// ---------------- T[i,:] = sum over out-edges e=(i,j): w_e * Sp[j,:]  (row in LDS) -------
// 32-lane sub-waves: 8 segments in flight (deg~33 -> ~full lane utilization).
__global__ void spgemm1_kernel(const int* e_dst, const float* ew,
                               const int* off_src, const int* eid_src,
                               const int* cp, const float* sp, float* T){
    __shared__ float row[KK];
    __shared__ int   jlo_[SEGCAP];
    __shared__ int   jhi_[SEGCAP];
    __shared__ float w_[SEGCAP];
    int i = blockIdx.x;
    for (int c = threadIdx.x; c < KK; c += 256) row[c] = 0.f;
    int lo = off_src[i], hi = off_src[i+1];
    int L = hi - lo;
    int Ls = (L <= SEGCAP) ? L : SEGCAP;
    for (int t = threadIdx.x; t < Ls; t += 256){
        int e = eid_src[lo + t];
        int j = edst(e_dst, e);
        jlo_[t] = off_src[j];
        jhi_[t] = off_src[j+1];
        w_[t]   = (e < E0S) ? ew[e] : 1.0f;
    }
    __syncthreads();
    int sw = threadIdx.x >> 5, ln = threadIdx.x & 31;
    for (int t = sw; t < Ls; t += 8){
        float w1 = w_[t];
        for (int u = jlo_[t] + ln; u < jhi_[t]; u += 32){
            int c = cp[u];                       // contiguous stream
            if (c >= 0) atomicAdd(&row[c], w1 * sp[u]);
        }
    }
    for (int t = Ls + sw; t < L; t += 8){   // overflow fallback
        int e = eid_src[lo + t];
        int j = edst(e_dst, e);
        float w1 = (e < E0S) ? ew[e] : 1.0f;
        int jlo = off_src[j], jhi = off_src[j+1];
        for (int u = jlo + ln; u < jhi; u += 32){
            int c = cp[u];
            if (c >= 0) atomicAdd(&row[c], w1 * sp[u]);
        }
    }
    __syncthreads();
    float* Trow = T + (size_t)i * KK;
    for (int c = threadIdx.x; c < KK; c += 256) Trow[c] = row[c];
}

// ---------------- A_c[r, chunk] = sum over dst-positions of perm[r]: ssd * T[isd, chunk] ----
// 16 chunks of 128 cols (2 MB T-slice << 4 MB XCD L2). grid dim3(8, 512), 256 thr:
// chunk = bx + 8*(by>>8) -> linear id % 8 = bx pins each chunk's slice to one XCD.
// Each block: 8 rows (32 lanes/row), floatx4 (4 cols) per thread. Nontemporal Ac store.
__global__ void spgemm2_kernel(const int* perm, const int* off_dst,
                               const int* isd, const float* ssd,
                               const float* T, float* Ac){
    __shared__ int   is_[8][SEGCAP];
    __shared__ float ss_[8][SEGCAP];
    int bx = blockIdx.x;              // 0..7
    int by = blockIdx.y;              // 0..511
    int half = by >> 8;               // 0 or 1
    int rr   = by & 255;              // 0..255
    int sub  = threadIdx.x >> 5;      // 0..7 (row within block)
    int lane = threadIdx.x & 31;      // 0..31
    int r = rr * 8 + sub;
    int chunk = bx + 8 * half;        // 0..15
    int c0 = chunk * 128 + lane * 4;  // 4 consecutive columns per thread
    int node = perm[r];
    int lo = off_dst[node], hi = off_dst[node+1];
    int L = hi - lo;
    int Ls = (L <= SEGCAP) ? L : SEGCAP;
    for (int t = lane; t < Ls; t += 32){
        is_[sub][t] = isd[lo + t];
        ss_[sub][t] = ssd[lo + t];
    }
    __syncthreads();
    floatx4 acc = {0.f, 0.f, 0.f, 0.f};
    int t = 0;
    for (; t + 1 < Ls; t += 2){
        floatx4 a = *(const floatx4*)&T[(size_t)is_[sub][t]   * KK + c0];
        floatx4 b = *(const floatx4*)&T[(size_t)is_[sub][t+1] * KK + c0];
        float s0 = ss_[sub][t], s1 = ss_[sub][t+1];
        acc.x = fmaf(s0, a.x, acc.x); acc.y = fmaf(s0, a.y, acc.y);
        acc.z = fmaf(s0, a.z, acc.z); acc.w = fmaf(s0, a.w, acc.w);
        acc.x = fmaf(s1, b.x, acc.x); acc.y = fmaf(s1, b.y, acc.y);
        acc.z = fmaf(s1, b.z, acc.z); acc.w = fmaf(s1, b.w, acc.w);
    }
    for (; t < Ls; ++t){
        floatx4 a = *(const floatx4*)&T[(size_t)is_[sub][t] * KK + c0];
        float s0 = ss_[sub][t];
        acc.x = fmaf(s0, a.x, acc.x); acc.y = fmaf(s0, a.y, acc.y);
        acc.z = fmaf(s0, a.z, acc.z); acc.w = fmaf(s0, a.w, acc.w);
    }
    for (t = Ls; t < L; ++t){            // overflow fallback
        floatx4 a = *(const floatx4*)&T[(size_t)isd[lo + t] * KK + c0];
        float s0 = ssd[lo + t];
        acc.x = fmaf(s0, a.x, acc.x); acc.y = fmaf(s0, a.y, acc.y);
        acc.z = fmaf(s0, a.z, acc.z); acc.w = fmaf(s0, a.w, acc.w);
    }
    if (r - c0 >= 0 && r - c0 < 4){      // zero the diagonal element
        if (r - c0 == 0) acc.x = 0.f;
        else if (r - c0 == 1) acc.y = 0.f;
        else if (r - c0 == 2) acc.z = 0.f;
        else acc.w = 0.f;
    }
    __builtin_nontemporal_store(acc, (floatx4*)&Ac[(size_t)r * KK + c0]);
}

// ---------------- fallback: edge-pair outer products with global atomics ----------------
__global__ void ac_kernel(const int* e_src, const int* e_dst, const float* ew,
                          const int* off_src,
                          const int* cp, const float* sp, float* Ac){
    int e1 = blockIdx.x * blockDim.x + threadIdx.x;
    if (e1 >= NE) return;
    int i = (e1 < E0S) ? e_src[e1] : e1 - E0S;
    int j = (e1 < E0S) ? e_dst[e1] : e1 - E0S;
    float w1 = (e1 < E0S) ? ew[e1] : 1.0f;
    int ilo = off_src[i], ihi = off_src[i+1];
    int jlo = off_src[j], jhi = off_src[j+1];
    for (int ta = ilo; ta < ihi; ++ta){
        int ca = cp[ta];
        if (ca < 0) continue;
        float va = sp[ta] * w1;
        float* rowp = Ac + (size_t)ca * KK;
        for (int tb = jlo; tb < jhi; ++tb){
            int cb = cp[tb];
            if (cb < 0) continue;
            atomicAdd(&rowp[cb], va * sp[tb]);
        }
    }
}

// ---------------- zero diagonal of A_c (fallback path) ----------------
__global__ void diag_kernel(float* Ac){
    int r = blockIdx.x * blockDim.x + threadIdx.x;
    if (r < KK) Ac[(size_t)r * KK + r] = 0.f;
}

extern "C" void kernel_launch(void* const* d_in, const int* in_sizes, int n_in,
                              void* d_out, int out_size, void* d_ws, size_t ws_size,
                              hipStream_t stream){
    const float* x     = (const float*)d_in[0];
    const int*   ei    = (const int*)d_in[1];
    const float* ew    = (const float*)d_in[2];
    const float* lin_w = (const float*)d_in[3];
    const float* lin_b = (const float*)d_in[4];
    const float* att_w = (const float*)d_in[5];
    const float* att_b = (const float*)d_in[6];
    const float* le1_w = (const float*)d_in[7];
    const float* le1_b = (const float*)d_in[8];
    const float* le2_w = (const float*)d_in[9];
    const float* le3_w = (const float*)d_in[10];
    const float* le3_b = (const float*)d_in[11];

    const int* e_src = ei;
    const int* e_dst = ei + E0S;

    float* out    = (float*)d_out;
    float* x_out  = out;                                     // KK*DD
    float* Ac     = out + (size_t)KK * DD;                   // KK*KK
    float* operm  = out + (size_t)KK * DD + (size_t)KK * KK; // KK

    // workspace carve-up (all 4-byte elements)
    char* wp = (char*)d_ws;
    auto alloc_i = [&](size_t n){ int* p = (int*)wp; wp += n * sizeof(int); return p; };
    auto alloc_f = [&](size_t n){ float* p = (float*)wp; wp += n * sizeof(float); return p; };

    int* deg_dst = alloc_i(NN);
    int* deg_src = alloc_i(NN);
    int* off_dst = alloc_i(NN + 1);
    int* off_src = alloc_i(NN + 1);
    int* cur_dst = alloc_i(NN);
    int* cur_src = alloc_i(NN);
    int* eid_dst = alloc_i(NE);
    int* eid_src = alloc_i(NE);
    int* colmap  = alloc_i(NN);
    int* perm    = alloc_i(KK);
    int* isd     = alloc_i(NE);    // src node per dst-CSR position
    int* cp      = alloc_i(NE);    // colmap[dst] per src-CSR position
    float* sp    = alloc_f(NE);    // sc per src-CSR position
    float* ssd   = alloc_f(NE);    // softmax score per dst-CSR position
    float* q_s   = alloc_f(NN);
    float* p_s   = alloc_f(NN);
    float* a_    = alloc_f(NN);
    float* b_    = alloc_f(NN);
    float* c_    = alloc_f(NN);
    float* fit   = alloc_f(NN);
    float* sc    = alloc_f(NE);
    float* x_q   = alloc_f((size_t)NN * DD);
    float* xn    = alloc_f((size_t)NN * DD);
    float* T     = alloc_f((size_t)NN * KK);   // 32 MB dense intermediate for A_c
    bool dense_ok = ((size_t)(wp - (char*)d_ws) <= ws_size);
    (void)n_in; (void)in_sizes; (void)out_size;

    const int EB = (NE + 255) / 256;

    init_kernel<<<dense_ok ? 64 : 2048, 256, 0, stream>>>(deg_dst, deg_src, colmap, Ac,
                                                          dense_ok ? 0 : 1);
    count_kernel<<<EB, 256, 0, stream>>>(e_src, e_dst, deg_dst, deg_src);
    scan_kernel<<<2, 1024, 0, stream>>>(deg_dst, off_dst, cur_dst, deg_src, off_src, cur_src);
    fill_kernel<<<EB, 256, 0, stream>>>(e_src, e_dst, cur_dst, cur_src, eid_dst, eid_src);
    segsort_kernel<<<(2 * NN) / 4, 256, 0, stream>>>(off_dst, eid_dst, off_src, eid_src, e_src, isd);
    segmax_kernel<<<NN / 4, 256, 0, stream>>>(x, off_dst, isd, x_q);
    linnd_kernel<<<NN / LR2, 256, 0, stream>>>(x, x_q, lin_w, lin_b, att_w, q_s, p_s);
    softxn_kernel<<<NN / 4, 256, 0, stream>>>(x, off_dst, eid_dst, isd, q_s, p_s, att_b,
                                              le1_w, le1_b, le2_w, le3_w, le3_b,
                                              sc, ssd, xn, a_, b_, c_);
    fitness_kernel<<<NN / 4, 256, 0, stream>>>(off_dst, isd, a_, b_, c_, fit);
    topk_kernel<<<1, 1024, 0, stream>>>(fit, perm, colmap, operm);
    xoutprep_kernel<<<KK + EB, 256, 0, stream>>>(xn, fit, perm, x_out,
                                                 eid_src, e_dst, colmap, sc, cp, sp);
    if (dense_ok){
        spgemm1_kernel<<<NN, 256, 0, stream>>>(e_dst, ew, off_src, eid_src, cp, sp, T);
        spgemm2_kernel<<<dim3(8, 512), 256, 0, stream>>>(perm, off_dst, isd, ssd, T, Ac);
    } else {
        ac_kernel<<<EB, 256, 0, stream>>>(e_src, e_dst, ew, off_src, cp, sp, Ac);
        diag_kernel<<<(KK + 255) / 256, 256, 0, stream>>>(Ac);
    }
}